// Round 5
// baseline (2432.930 us; speedup 1.0000x reference)
//
#include <hip/hip_runtime.h>
#include <hip/hip_bf16.h>
#include <math.h>

#define B_ 256
#define L_ 512
#define V_ 256
#define E_ 256
#define H_ 1024
#define NSTEP_ 513   // flag-step stride (H_1 .. H_512)

typedef float  f32x4  __attribute__((ext_vector_type(4)));
typedef short  bf16x8 __attribute__((ext_vector_type(8)));

static __device__ __forceinline__ ushort f2bf(float v) {
    __hip_bfloat16 b = __float2bfloat16(v);
    return *reinterpret_cast<ushort*>(&b);
}

// ---------- prep: transpose f32 [R][C] -> bf16 [C][R] ----------
__global__ void k_transpose_bf16(const float* __restrict__ in, ushort* __restrict__ out,
                                 int R, int C) {
    __shared__ float tile[64][65];
    int bx = blockIdx.x;           // over C/64
    int by = blockIdx.y;           // over R/64
    int tid = threadIdx.x;
    int g = tid >> 6, l = tid & 63;
    for (int i = 0; i < 16; ++i) {
        int r = g * 16 + i;
        tile[r][l] = in[(size_t)(by * 64 + r) * C + bx * 64 + l];
    }
    __syncthreads();
    for (int i = 0; i < 16; ++i) {
        int c = g * 16 + i;
        out[(size_t)(bx * 64 + c) * R + by * 64 + l] = f2bf(tile[l][c]);
    }
}

// ---------- prep: f32 -> bf16 copy ----------
__global__ void k_f32_to_bf16(const float* __restrict__ in, ushort* __restrict__ out, int n) {
    int i = blockIdx.x * blockDim.x + threadIdx.x;
    if (i < n) out[i] = f2bf(in[i]);
}

// ---------- prep: zero the flag array ----------
__global__ void k_zero(unsigned* __restrict__ p, int n) {
    int i = blockIdx.x * blockDim.x + threadIdx.x;
    if (i < n) p[i] = 0u;
}

// ---------- prep: proj[t][h] = sum_e emb[t][e] * W_e[e][h]  (f32) ----------
__global__ void k_proj(const float* __restrict__ emb, const float* __restrict__ We,
                       float* __restrict__ proj) {
    __shared__ float er[E_];
    int t = blockIdx.x;
    int h = blockIdx.y * 256 + threadIdx.x;
    er[threadIdx.x] = emb[t * E_ + threadIdx.x];   // blockDim.x == 256 == E_
    __syncthreads();
    float acc = 0.f;
#pragma unroll 8
    for (int e = 0; e < E_; ++e) acc += er[e] * We[(size_t)e * H_ + h];
    proj[(size_t)t * H_ + h] = acc;
}

// ---------- persistent scan kernel ----------
// 256 blocks, 1/CU (LDS-forced). Block (rg=bid&7, cg=bid>>3) owns h rows
// [rg*32,+32) x cols [cg*32,+32). Assignment from blockIdx ONLY (no placement
// assumptions — R4's XCD-ticket scheme deadlocked). Exchange at the L3
// coherence point: sc0 sc1 data/flag stores after vmcnt(0) drain + barrier;
// sc0 sc1 polls/loads (R3-proven). Per-producer flags (no atomic RMW chain).
// Wave 0 polls step s while waves 1-3 compute logits of step s-2 (B-phase),
// taking B off the critical path. x/proj gathers prefetched before the poll.
__global__ __launch_bounds__(256, 1) void k_scan(
    const int* __restrict__ x, const float* __restrict__ proj,
    const ushort* __restrict__ WhT, const ushort* __restrict__ WoT,
    ushort* __restrict__ ring, float* __restrict__ logits,
    float* __restrict__ final_h, unsigned* __restrict__ flags)
{
    __shared__ ushort lds_w[32 * 1024];   // W_h^T cols slice, swizzled (64KB), persistent
    __shared__ ushort lds_h[32 * 1024];   // H_s rows slice, swizzled (64KB), per step
    __shared__ float  red[256 * 5];       // B-phase reduce, stride-5 (5KB)
    __shared__ ushort stile[32 * 32];     // A-phase store repack (2KB)

    int tid = threadIdx.x;
    int w = tid >> 6, lane = tid & 63;
    int l15 = lane & 15, l4 = lane >> 4;
    int bid = blockIdx.x;
    int rg = bid & 7;             // row-group
    int cg = bid >> 3;            // 0..31 col-group
    int r0 = rg * 32, c0 = cg * 32;

    // --- preload W slice once (read-only, kernel-boundary coherent)
    {
        const char* wsrc = (const char*)(WhT + (size_t)c0 * H_);
        char* wd = (char*)lds_w;
        for (int i = 0; i < 16; ++i) {
            int chunk = (w * 16 + i) * 1024;
            int o = chunk + lane * 16;
            int row = o >> 11, b = o & 2047;
            int so = row * 2048 + (b ^ ((row & 7) << 4));
            __builtin_amdgcn_global_load_lds(
                (const __attribute__((address_space(1))) void*)(wsrc + so),
                (__attribute__((address_space(3))) void*)(wd + chunk), 16, 0, 0);
        }
    }

    // A-phase constants
    int a = w >> 1, bc = w & 1;
    int arow = a * 16 + l15;
    int brow = bc * 16 + l15;
    const char* ha = (const char*)lds_h + arow * 2048;
    const char* wa = (const char*)lds_w + brow * 2048;
    int as = (arow & 7) << 4, bs = (brow & 7) << 4;
    int gcol = c0 + bc * 16 + l15;

    // B-phase constants: block does logits rows r0+(cg&1)*16..+16, vocab cols (cg>>1)*16..+16
    int lrg = cg & 1, vcol0 = (cg >> 1) * 16;
    int srow = lrg * 16 + l15;
    const char* hbp = (const char*)lds_h + srow * 2048;
    int hs2 = (srow & 7) << 4;
    const ushort* wo = WoT + (size_t)(vcol0 + l15) * H_;
    // K-chunk split over waves 1..3: 11/11/10 of 32
    int bbase = (w == 1) ? 0 : (w == 2) ? 11 : 22;
    int bcnt  = (w == 3) ? 10 : 11;

    for (int s = 0; s <= NSTEP_; ++s) {
        // --- prefetch x/proj gathers for A(s) before the poll (read-only data)
        float pv[4];
        if (s < L_) {
#pragma unroll
            for (int j = 0; j < 4; ++j) {
                int grow = r0 + a * 16 + l4 * 4 + j;
                pv[j] = proj[(size_t)x[grow * L_ + s] * H_ + gcol];
            }
        }

        // --- wave0: poll 32 per-producer flags for H_s; waves1-3: B-phase (s-2)
        if (w == 0) {
            if (s >= 1 && s <= L_) {
                const unsigned* fp = flags + ((size_t)rg * NSTEP_ + s) * 32 + lane;
                unsigned v = 1u;
                while (true) {
                    if (lane < 32) {
                        asm volatile("global_load_dword %0, %1, off sc0 sc1\n\t"
                                     "s_waitcnt vmcnt(0)"
                                     : "=v"(v) : "v"(fp) : "memory");
                    }
                    if (__ballot(v != 0u) == ~0ull) break;
                }
            }
        } else if (s >= 2) {
            // lds_h currently holds H_{s-1}; compute its W_o product -> logits col s-2
            f32x4 lacc = {0.f, 0.f, 0.f, 0.f};
            for (int kk = 0; kk < bcnt; ++kk) {
                int k = (bbase + kk) * 32 + l4 * 8;
                bf16x8 af = *(const bf16x8*)(hbp + ((2 * k) ^ hs2));
                bf16x8 bf = *(const bf16x8*)(wo + k);
                lacc = __builtin_amdgcn_mfma_f32_16x16x32_bf16(af, bf, lacc, 0, 0, 0);
            }
#pragma unroll
            for (int j = 0; j < 4; ++j) red[tid * 5 + j] = lacc[j];
        }
        __syncthreads();   // poll done; B done reading lds_h; red[] complete

        // --- stage H_s: issue sc0 sc1 loads first (latency overlaps logits store)
        f32x4 tv[16];
        if (s <= L_) {
            const char* hsrc = (const char*)(ring + (size_t)(s & 1) * B_ * H_
                                             + (size_t)r0 * H_) + tid * 16;
#pragma unroll
            for (int i = 0; i < 16; ++i) {
                asm volatile("global_load_dwordx4 %0, %1, off sc0 sc1"
                             : "=v"(tv[i]) : "v"(hsrc + i * 4096) : "memory");
            }
        }
        // --- wave0 finalizes logits col s-2 while the stage loads fly
        if (w == 0 && s >= 2) {
            int growb = r0 + lrg * 16 + l4 * 4;
#pragma unroll
            for (int j = 0; j < 4; ++j) {
                float ssum = red[(64 + lane) * 5 + j] + red[(128 + lane) * 5 + j]
                           + red[(192 + lane) * 5 + j];
                logits[((size_t)(growb + j) * L_ + (s - 2)) * V_ + vcol0 + l15] = ssum;
            }
        }
        if (s <= L_) {
            asm volatile("s_waitcnt vmcnt(0)" ::: "memory");
#pragma unroll
            for (int i = 0; i < 16; ++i) {
                int o = i * 4096 + tid * 16;
                int row = o >> 11, b = o & 2047;
                *(f32x4*)((char*)lds_h + row * 2048 + (b ^ ((row & 7) << 4))) = tv[i];
            }
        }
        __syncthreads();   // lds_h = H_s

        // --- A phase: H_{s+1} tile = tanh(pv + H_s @ W_h)
        if (s < L_) {
            f32x4 acc0 = {0.f, 0.f, 0.f, 0.f};
            f32x4 acc1 = {0.f, 0.f, 0.f, 0.f};
#pragma unroll
            for (int kk = 0; kk < 32; kk += 2) {
                int kb0 = (kk * 32 + l4 * 8) * 2;
                int kb1 = ((kk + 1) * 32 + l4 * 8) * 2;
                bf16x8 af0 = *(const bf16x8*)(ha + (kb0 ^ as));
                bf16x8 bf0 = *(const bf16x8*)(wa + (kb0 ^ bs));
                bf16x8 af1 = *(const bf16x8*)(ha + (kb1 ^ as));
                bf16x8 bf1 = *(const bf16x8*)(wa + (kb1 ^ bs));
                acc0 = __builtin_amdgcn_mfma_f32_16x16x32_bf16(af0, bf0, acc0, 0, 0, 0);
                acc1 = __builtin_amdgcn_mfma_f32_16x16x32_bf16(af1, bf1, acc1, 0, 0, 0);
            }
#pragma unroll
            for (int j = 0; j < 4; ++j) {
                int lrow = a * 16 + l4 * 4 + j;
                float hv = tanhf((acc0[j] + acc1[j]) + pv[j]);
                stile[lrow * 32 + bc * 16 + l15] = f2bf(hv);
                if (s == L_ - 1) final_h[(size_t)(r0 + lrow) * H_ + gcol] = hv;
            }
            __syncthreads();       // stile complete
            if (tid < 128) {
                int row = tid >> 2, seg = tid & 3;
                f32x4 d = *(const f32x4*)&stile[row * 32 + seg * 8];
                char* dst = (char*)(ring + (size_t)((s + 1) & 1) * B_ * H_
                                    + (size_t)(r0 + row) * H_ + c0 + seg * 8);
                asm volatile("global_store_dwordx4 %0, %1, off sc0 sc1"
                             :: "v"(dst), "v"(d) : "memory");
            }
            asm volatile("s_waitcnt vmcnt(0)" ::: "memory");   // data at coherence point
            __syncthreads();                                   // ALL producers' stores drained
            if (tid == 0) {
                unsigned* fdst = flags + ((size_t)rg * NSTEP_ + (s + 1)) * 32 + cg;
                unsigned one = 1u;
                asm volatile("global_store_dword %0, %1, off sc0 sc1"
                             :: "v"(fdst), "v"(one) : "memory");
            }
        }
    }
}

extern "C" void kernel_launch(void* const* d_in, const int* in_sizes, int n_in,
                              void* d_out, int out_size, void* d_ws, size_t ws_size,
                              hipStream_t stream)
{
    const int*   x   = (const int*)d_in[0];
    const float* hid = (const float*)d_in[1];
    const float* emb = (const float*)d_in[2];
    const float* We  = (const float*)d_in[3];
    const float* Wh  = (const float*)d_in[4];
    const float* Wo  = (const float*)d_in[5];

    float* logits  = (float*)d_out;                       // [B][L][V] f32
    float* final_h = logits + (size_t)B_ * L_ * V_;       // [B][H] f32

    char* ws = (char*)d_ws;
    float*    proj  = (float*)(ws);                                   // 1 MB   f32 [V][H]
    ushort*   WhT   = (ushort*)(ws + (1u << 20));                     // 2 MB   bf16 [H][H]^T
    ushort*   WoT   = (ushort*)(ws + 3u * (1u << 20));                // 0.5 MB bf16 [V][H]^T
    ushort*   ring  = (ushort*)(ws + 3u * (1u << 20) + (1u << 19));   // 1 MB   bf16 2x[B][H]
    unsigned* flags = (unsigned*)(ws + 4u * (1u << 20) + (1u << 19)); // 513 KB u32 [8][513][32]

    // prep (stream-ordered before the persistent kernel)
    k_zero<<<dim3(NSTEP_), 256, 0, stream>>>(flags, 8 * NSTEP_ * 32);
    k_transpose_bf16<<<dim3(16, 16), 256, 0, stream>>>(Wh, WhT, H_, H_);
    k_transpose_bf16<<<dim3(4, 16),  256, 0, stream>>>(Wo, WoT, H_, V_);
    k_f32_to_bf16<<<dim3(1024), 256, 0, stream>>>(hid, ring, B_ * H_);   // H_0 -> slot 0
    k_proj<<<dim3(256, 4), 256, 0, stream>>>(emb, We, proj);

    // one persistent kernel does all 512 steps + fused logits
    k_scan<<<dim3(256), 256, 0, stream>>>(x, proj, WhT, WoT, ring,
                                          logits, final_h, flags);
}